// Round 8
// baseline (110.156 us; speedup 1.0000x reference)
//
#include <hip/hip_runtime.h>

// Chamfer-with-normals, B=8, C=6 (3 pos + 3 nrm), N=4096, fp32.
// d[i][j] = aa_i + (bb_j + W) + r_i.c_j,  r=(-2p_i, -W bn_i), c=(q_j, an_j)
// (cross-indexed normals; MFMA f16 hi/lo formulation verified absmax=0 R6/R7).
//
// R8: (1) rt 8->16 (block = 1024 rows x 1024-col split, 256 blocks = 1/CU):
// LDS b-frag reads per CU halve (512->256 b128, ds-reads/MFMA ~ 1/rt) while
// MFMA stays 4.9k cyc/SIMD. (2) epilogue l16-min via DPP row_ror v_min (VALU
// pipe) replacing shfl_xor (1024 ds_bpermute/CU on the saturated DS pipe).
// (3) single worker dispatch: cross-block reduce runs in a two-level
// last-block tail (per-bd arrival counters, device-scope fences, counters
// zeroed by a tiny hipMemsetAsync — capturable). Final winner writes out
// directly; no atomic zero-init dance.
//   A32 = [rh6|rl6|rh6|rl6| 1 1 ah al |0000], B32 = [ch6|ch6|cl6|cl6| bh bl 1 1 |0000]
// Layouts m89/m120-verified; D[row=quad*4+reg][col=lane&15].

constexpr int   NPTS  = 4096;
constexpr int   CPB   = 6;
constexpr int   BATCH = 8;
constexpr float W     = 0.001f;

typedef _Float16 f16x8 __attribute__((ext_vector_type(8)));
typedef float    f32x4 __attribute__((ext_vector_type(4)));

#define MFMA32(A_, B_, C_) __builtin_amdgcn_mfma_f32_16x16x32_f16((A_), (B_), (C_), 0, 0, 0)

__device__ inline void fsplit(float x, _Float16& h, _Float16& l) {
    h = (_Float16)x;
    l = (_Float16)(x - (float)h);
}

// min with row_ror:N DPP (16-lane row rotation; all lanes valid) — VALU pipe.
template<int CTRL>
__device__ inline float minror(float v) {
    int s = __float_as_int(v);
    int r = __builtin_amdgcn_update_dpp(s, s, CTRL, 0xF, 0xF, false);
    return fminf(v, __int_as_float(r));
}

// Grid: x = rg*4 + s (rg: 4 groups of 1024 rows; s: 4 splits of 1024 cols),
// y = batch, z = dir  => 256 blocks = 1/CU. 256 thr; wave owns 256 rows (rt=16).
__global__ __launch_bounds__(256, 1) void chamfer_fused_kernel(
    const float* __restrict__ A, const float* __restrict__ B,
    float* __restrict__ partial, unsigned* __restrict__ ctrl,
    float* __restrict__ out)
{
    const int dir = blockIdx.z, batch = blockIdx.y, bd = dir * BATCH + batch;
    const int rg = blockIdx.x >> 2, s = blockIdx.x & 3;
    const int tid = threadIdx.x, w = tid >> 6, lane = tid & 63;
    const int quad = lane >> 4, l16 = lane & 15;
    const float* rowPos = dir ? B : A;
    const float* rowNrm = dir ? A : B;
    const float* colPos = dir ? A : B;
    const float* colNrm = dir ? B : A;
    const int bb = batch * CPB * NPTS;
    const _Float16 one = (_Float16)1.f, zz = (_Float16)0.f;

    // [k-plane][col][8 f16]: plane p at p*8192 f16 (16KB). Staging writes and
    // b-frag reads are both lane-consecutive 16B bursts (conflict-free b128).
    __shared__ alignas(16) _Float16 lds[4 * 1024 * 8];   // 64 KB

    // ---- stage this block's 1024 cols (4 cols per thread)
#pragma unroll
    for (int p = 0; p < 4; ++p) {
        const int j  = p * 256 + tid;
        const int cj = s * 1024 + j;
        const float q0 = colPos[bb + 0*NPTS + cj], q1 = colPos[bb + 1*NPTS + cj],
                    q2 = colPos[bb + 2*NPTS + cj];
        const float n0 = colNrm[bb + 3*NPTS + cj], n1 = colNrm[bb + 4*NPTS + cj],
                    n2 = colNrm[bb + 5*NPTS + cj];
        const float c6[6] = {q0, q1, q2, n0, n1, n2};
        const float bias = fmaf(q0, q0, fmaf(q1, q1, q2*q2)) + W;
        _Float16 ch[6], cl[6], bh, bl;
#pragma unroll
        for (int c = 0; c < 6; ++c) fsplit(c6[c], ch[c], cl[c]);
        fsplit(bias, bh, bl);
        f16x8 v0 = {ch[0], ch[1], ch[2], ch[3], ch[4], ch[5], ch[0], ch[1]};
        f16x8 v1 = {ch[2], ch[3], ch[4], ch[5], cl[0], cl[1], cl[2], cl[3]};
        f16x8 v2 = {cl[4], cl[5], cl[0], cl[1], cl[2], cl[3], cl[4], cl[5]};
        f16x8 v3 = {bh, bl, one, one, zz, zz, zz, zz};
        *(f16x8*)&lds[0 * 8192 + j * 8] = v0;
        *(f16x8*)&lds[1 * 8192 + j * 8] = v1;
        *(f16x8*)&lds[2 * 8192 + j * 8] = v2;
        *(f16x8*)&lds[3 * 8192 + j * 8] = v3;
    }

    // ---- A-frags: rt=16 row-tiles per wave (wave owns 256 rows)
    f16x8 a[16];
#pragma unroll
    for (int rt = 0; rt < 16; ++rt) {
        const int row = rg * 1024 + w * 256 + rt * 16 + l16;
        const float p0 = rowPos[bb + 0*NPTS + row], p1 = rowPos[bb + 1*NPTS + row],
                    p2 = rowPos[bb + 2*NPTS + row];
        const float rn0 = rowNrm[bb + 3*NPTS + row], rn1 = rowNrm[bb + 4*NPTS + row],
                    rn2 = rowNrm[bb + 5*NPTS + row];
        const float r6[6] = {-2.f*p0, -2.f*p1, -2.f*p2, -W*rn0, -W*rn1, -W*rn2};
        const float aa = fmaf(p0, p0, fmaf(p1, p1, p2*p2));
        _Float16 rh[6], rl[6], ah, al;
#pragma unroll
        for (int c = 0; c < 6; ++c) fsplit(r6[c], rh[c], rl[c]);
        fsplit(aa, ah, al);
        f16x8 af;
        if (quad == 0)      af = f16x8{rh[0], rh[1], rh[2], rh[3], rh[4], rh[5], rl[0], rl[1]};
        else if (quad == 1) af = f16x8{rl[2], rl[3], rl[4], rl[5], rh[0], rh[1], rh[2], rh[3]};
        else if (quad == 2) af = f16x8{rh[4], rh[5], rl[0], rl[1], rl[2], rl[3], rl[4], rl[5]};
        else                af = f16x8{one, one, ah, al, zz, zz, zz, zz};
        a[rt] = af;
    }

    float m[16][4];
#pragma unroll
    for (int rt = 0; rt < 16; ++rt)
#pragma unroll
        for (int r_ = 0; r_ < 4; ++r_) m[rt][r_] = 3.4e38f;

    __syncthreads();

    const _Float16* lq = &lds[quad * 8192];
    const f32x4 z = {0.f, 0.f, 0.f, 0.f};
#pragma unroll 2
    for (int ct = 0; ct < 64; ct += 2) {
        const f16x8 b0 = *(const f16x8*)&lq[(ct * 16 + l16) * 8];
        const f16x8 b1 = *(const f16x8*)&lq[((ct + 1) * 16 + l16) * 8];
#pragma unroll
        for (int rt = 0; rt < 16; ++rt) {
            f32x4 acc0 = MFMA32(a[rt], b0, z);
            f32x4 acc1 = MFMA32(a[rt], b1, z);
#pragma unroll
            for (int r_ = 0; r_ < 4; ++r_)
                m[rt][r_] = fminf(m[rt][r_], fminf(acc0[r_], acc1[r_]));  // v_min3
        }
    }

    // ---- col-min over l16 via DPP row_ror (VALU pipe, no DS traffic)
#pragma unroll
    for (int rt = 0; rt < 16; ++rt)
#pragma unroll
        for (int r_ = 0; r_ < 4; ++r_) {
            float v = m[rt][r_];
            v = minror<0x121>(v);   // ror 1
            v = minror<0x122>(v);   // ror 2
            v = minror<0x124>(v);   // ror 4
            v = minror<0x128>(v);   // ror 8
            m[rt][r_] = v;
        }
    if (l16 == 0) {
        float* pb = partial + (size_t)(s * 16 + bd) * NPTS + rg * 1024 + w * 256;
#pragma unroll
        for (int rt = 0; rt < 16; ++rt)
            *(float4*)(pb + rt * 16 + quad * 4) =
                make_float4(m[rt][0], m[rt][1], m[rt][2], m[rt][3]);
    }

    // ================= last-block tail (two-level) =================
    // ctrl: [0..15] per-bd arrival counters, [16] finisher counter; +sumacc.
    float* sumacc = (float*)(ctrl + 17);
    __syncthreads();                    // all partial stores issued (drained at barrier)
    int* flag = (int*)lds;              // reuse LDS (everyone past the barrier)
    if (tid == 0) {
        __threadfence();                // release partials (L2 writeback, device scope)
        const unsigned old = atomicAdd(&ctrl[bd], 1u);
        flag[0] = (old == 15u);         // 16 blocks per bd (4 rg x 4 s)
    }
    __syncthreads();
    if (!flag[0]) return;

    // Winner block: fold this bd's 4 splits (4096 rows), sum row-mins.
    __threadfence();                    // acquire (invalidate stale caches)
    float mysum = 0.f;
#pragma unroll
    for (int i = 0; i < 16; ++i) {
        const int row = i * 256 + tid;
        float v = partial[(size_t)(0 * 16 + bd) * NPTS + row];
        v = fminf(v, partial[(size_t)(1 * 16 + bd) * NPTS + row]);
        v = fminf(v, partial[(size_t)(2 * 16 + bd) * NPTS + row]);
        v = fminf(v, partial[(size_t)(3 * 16 + bd) * NPTS + row]);
        mysum += v;
    }
    for (int off = 32; off; off >>= 1)
        mysum += __shfl_down(mysum, off, 64);
    __syncthreads();                    // reuse lds as float scratch
    float* sred = (float*)lds;
    if (lane == 0) sred[w] = mysum;
    __syncthreads();
    if (tid == 0) {
        const float bdsum = sred[0] + sred[1] + sred[2] + sred[3];
        atomicAdd(sumacc, bdsum);
        __threadfence();                // order sumacc add before finisher count
        const unsigned old2 = atomicAdd(&ctrl[16], 1u);
        if (old2 == 15u) {              // all 16 bd sums are in
            const float total = atomicAdd(sumacc, 0.f);   // coherent read-back
            out[0] = total * 0.125f;    // /B
        }
    }
}

extern "C" void kernel_launch(void* const* d_in, const int* in_sizes, int n_in,
                              void* d_out, int out_size, void* d_ws, size_t ws_size,
                              hipStream_t stream) {
    const float* A = (const float*)d_in[0];
    const float* B = (const float*)d_in[1];
    float* out     = (float*)d_out;

    // ws: [partial 4s x 16bd x 4096 f32 = 1MB][ctrl: 17 u32 + 1 f32]
    float*    partial = (float*)d_ws;
    unsigned* ctrl    = (unsigned*)((char*)d_ws + (size_t)1024 * 1024);

    hipMemsetAsync(ctrl, 0, 256, stream);   // counters + sumacc = 0 (capturable)
    chamfer_fused_kernel<<<dim3(16, BATCH, 2), 256, 0, stream>>>(A, B, partial, ctrl, out);
}

// Round 9
// 91.037 us; speedup vs baseline: 1.2100x; 1.2100x over previous
//
#include <hip/hip_runtime.h>

// Chamfer-with-normals, B=8, C=6 (3 pos + 3 nrm), N=4096, fp32.
// d[i][j] = aa_i + (bb_j + W) + r_i.c_j,  r=(-2p_i, -W bn_i), c=(q_j, an_j)
// (cross-indexed normals; MFMA f16 hi/lo formulation verified absmax=0 R6-R8).
//
// R9 = R7 compute shape + R8 tail. R8's regression (85us) was a register cliff:
// rt=16 needed ~160 VGPRs for a[16]+m[16][4], compiler allocated 112 -> scratch
// spill, at 1 wave/SIMD (launch_bounds 256,1) every stall fully exposed.
// Revert to rt=8, 512 blocks = 2 blocks/CU, launch_bounds(256,2) (proven <41us
// in R7); keep R8's single-dispatch last-block reduction tail (verified exact)
// and DPP row_ror min epilogue (VALU pipe, no DS traffic).
//   A32 = [rh6|rl6|rh6|rl6| 1 1 ah al |0000], B32 = [ch6|ch6|cl6|cl6| bh bl 1 1 |0000]
// Layouts m89/m120-verified; D[row=quad*4+reg][col=lane&15].

constexpr int   NPTS  = 4096;
constexpr int   CPB   = 6;
constexpr int   BATCH = 8;
constexpr float W     = 0.001f;

typedef _Float16 f16x8 __attribute__((ext_vector_type(8)));
typedef float    f32x4 __attribute__((ext_vector_type(4)));

#define MFMA32(A_, B_, C_) __builtin_amdgcn_mfma_f32_16x16x32_f16((A_), (B_), (C_), 0, 0, 0)

__device__ inline void fsplit(float x, _Float16& h, _Float16& l) {
    h = (_Float16)x;
    l = (_Float16)(x - (float)h);
}

// min with row_ror:N DPP (16-lane row rotation; all lanes valid) — VALU pipe.
template<int CTRL>
__device__ inline float minror(float v) {
    int s = __float_as_int(v);
    int r = __builtin_amdgcn_update_dpp(s, s, CTRL, 0xF, 0xF, false);
    return fminf(v, __int_as_float(r));
}

// Grid: x = rg*4 + s (rg: 8 groups of 512 rows; s: 4 splits of 1024 cols),
// y = batch, z = dir => 512 blocks = 2/CU. 256 thr; wave owns 128 rows (rt=8).
__global__ __launch_bounds__(256, 2) void chamfer_fused_kernel(
    const float* __restrict__ A, const float* __restrict__ B,
    float* __restrict__ partial, unsigned* __restrict__ ctrl,
    float* __restrict__ out)
{
    const int dir = blockIdx.z, batch = blockIdx.y, bd = dir * BATCH + batch;
    const int rg = blockIdx.x >> 2, s = blockIdx.x & 3;
    const int tid = threadIdx.x, w = tid >> 6, lane = tid & 63;
    const int quad = lane >> 4, l16 = lane & 15;
    const float* rowPos = dir ? B : A;
    const float* rowNrm = dir ? A : B;
    const float* colPos = dir ? A : B;
    const float* colNrm = dir ? B : A;
    const int bb = batch * CPB * NPTS;
    const _Float16 one = (_Float16)1.f, zz = (_Float16)0.f;

    // [k-plane][col][8 f16]: plane p at p*8192 f16 (16KB). Staging writes and
    // b-frag reads are both lane-consecutive 16B bursts (conflict-free b128).
    __shared__ alignas(16) _Float16 lds[4 * 1024 * 8];   // 64 KB (2 blocks/CU = 128KB)

    // ---- stage this block's 1024 cols (4 cols per thread)
#pragma unroll
    for (int p = 0; p < 4; ++p) {
        const int j  = p * 256 + tid;
        const int cj = s * 1024 + j;
        const float q0 = colPos[bb + 0*NPTS + cj], q1 = colPos[bb + 1*NPTS + cj],
                    q2 = colPos[bb + 2*NPTS + cj];
        const float n0 = colNrm[bb + 3*NPTS + cj], n1 = colNrm[bb + 4*NPTS + cj],
                    n2 = colNrm[bb + 5*NPTS + cj];
        const float c6[6] = {q0, q1, q2, n0, n1, n2};
        const float bias = fmaf(q0, q0, fmaf(q1, q1, q2*q2)) + W;
        _Float16 ch[6], cl[6], bh, bl;
#pragma unroll
        for (int c = 0; c < 6; ++c) fsplit(c6[c], ch[c], cl[c]);
        fsplit(bias, bh, bl);
        f16x8 v0 = {ch[0], ch[1], ch[2], ch[3], ch[4], ch[5], ch[0], ch[1]};
        f16x8 v1 = {ch[2], ch[3], ch[4], ch[5], cl[0], cl[1], cl[2], cl[3]};
        f16x8 v2 = {cl[4], cl[5], cl[0], cl[1], cl[2], cl[3], cl[4], cl[5]};
        f16x8 v3 = {bh, bl, one, one, zz, zz, zz, zz};
        *(f16x8*)&lds[0 * 8192 + j * 8] = v0;
        *(f16x8*)&lds[1 * 8192 + j * 8] = v1;
        *(f16x8*)&lds[2 * 8192 + j * 8] = v2;
        *(f16x8*)&lds[3 * 8192 + j * 8] = v3;
    }

    // ---- A-frags: rt=8 row-tiles per wave (wave owns 128 rows)
    f16x8 a[8];
#pragma unroll
    for (int rt = 0; rt < 8; ++rt) {
        const int row = rg * 512 + (w * 8 + rt) * 16 + l16;
        const float p0 = rowPos[bb + 0*NPTS + row], p1 = rowPos[bb + 1*NPTS + row],
                    p2 = rowPos[bb + 2*NPTS + row];
        const float rn0 = rowNrm[bb + 3*NPTS + row], rn1 = rowNrm[bb + 4*NPTS + row],
                    rn2 = rowNrm[bb + 5*NPTS + row];
        const float r6[6] = {-2.f*p0, -2.f*p1, -2.f*p2, -W*rn0, -W*rn1, -W*rn2};
        const float aa = fmaf(p0, p0, fmaf(p1, p1, p2*p2));
        _Float16 rh[6], rl[6], ah, al;
#pragma unroll
        for (int c = 0; c < 6; ++c) fsplit(r6[c], rh[c], rl[c]);
        fsplit(aa, ah, al);
        f16x8 af;
        if (quad == 0)      af = f16x8{rh[0], rh[1], rh[2], rh[3], rh[4], rh[5], rl[0], rl[1]};
        else if (quad == 1) af = f16x8{rl[2], rl[3], rl[4], rl[5], rh[0], rh[1], rh[2], rh[3]};
        else if (quad == 2) af = f16x8{rh[4], rh[5], rl[0], rl[1], rl[2], rl[3], rl[4], rl[5]};
        else                af = f16x8{one, one, ah, al, zz, zz, zz, zz};
        a[rt] = af;
    }

    float m[8][4];
#pragma unroll
    for (int rt = 0; rt < 8; ++rt)
#pragma unroll
        for (int r_ = 0; r_ < 4; ++r_) m[rt][r_] = 3.4e38f;

    __syncthreads();

    const _Float16* lq = &lds[quad * 8192];
    const f32x4 z = {0.f, 0.f, 0.f, 0.f};
    for (int ct = 0; ct < 64; ct += 2) {
        const f16x8 b0 = *(const f16x8*)&lq[(ct * 16 + l16) * 8];
        const f16x8 b1 = *(const f16x8*)&lq[((ct + 1) * 16 + l16) * 8];
#pragma unroll
        for (int rt = 0; rt < 8; ++rt) {
            f32x4 acc0 = MFMA32(a[rt], b0, z);
            f32x4 acc1 = MFMA32(a[rt], b1, z);
#pragma unroll
            for (int r_ = 0; r_ < 4; ++r_)
                m[rt][r_] = fminf(m[rt][r_], fminf(acc0[r_], acc1[r_]));  // v_min3
        }
    }

    // ---- col-min over l16 via DPP row_ror (VALU pipe, no DS traffic)
#pragma unroll
    for (int rt = 0; rt < 8; ++rt)
#pragma unroll
        for (int r_ = 0; r_ < 4; ++r_) {
            float v = m[rt][r_];
            v = minror<0x121>(v);   // ror 1
            v = minror<0x122>(v);   // ror 2
            v = minror<0x124>(v);   // ror 4
            v = minror<0x128>(v);   // ror 8
            m[rt][r_] = v;
        }
    if (l16 == 0) {
        float* pb = partial + (size_t)(s * 16 + bd) * NPTS + rg * 512;
#pragma unroll
        for (int rt = 0; rt < 8; ++rt)
            *(float4*)(pb + (w * 8 + rt) * 16 + quad * 4) =
                make_float4(m[rt][0], m[rt][1], m[rt][2], m[rt][3]);
    }

    // ================= last-block tail (two-level, verified R8) =================
    // ctrl: [0..15] per-bd arrival counters, [16] finisher counter; +sumacc f32.
    float* sumacc = (float*)(ctrl + 17);
    __syncthreads();                    // all partial stores issued
    int* flag = (int*)lds;              // reuse LDS (everyone past the barrier)
    if (tid == 0) {
        __threadfence();                // release partials (device scope)
        const unsigned old = atomicAdd(&ctrl[bd], 1u);
        flag[0] = (old == 31u);         // 32 blocks per bd (8 rg x 4 s)
    }
    __syncthreads();
    if (!flag[0]) return;

    // Winner block: fold this bd's 4 splits (4096 rows), sum row-mins.
    __threadfence();                    // acquire
    float mysum = 0.f;
#pragma unroll
    for (int i = 0; i < 16; ++i) {
        const int row = i * 256 + tid;
        float v = partial[(size_t)(0 * 16 + bd) * NPTS + row];
        v = fminf(v, partial[(size_t)(1 * 16 + bd) * NPTS + row]);
        v = fminf(v, partial[(size_t)(2 * 16 + bd) * NPTS + row]);
        v = fminf(v, partial[(size_t)(3 * 16 + bd) * NPTS + row]);
        mysum += v;
    }
    for (int off = 32; off; off >>= 1)
        mysum += __shfl_down(mysum, off, 64);
    __syncthreads();                    // reuse lds as float scratch
    float* sred = (float*)lds;
    if (lane == 0) sred[w] = mysum;
    __syncthreads();
    if (tid == 0) {
        const float bdsum = sred[0] + sred[1] + sred[2] + sred[3];
        atomicAdd(sumacc, bdsum);
        __threadfence();                // order sumacc add before finisher count
        const unsigned old2 = atomicAdd(&ctrl[16], 1u);
        if (old2 == 15u) {              // all 16 bd sums are in
            const float total = atomicAdd(sumacc, 0.f);   // coherent read-back
            out[0] = total * 0.125f;    // /B
        }
    }
}

extern "C" void kernel_launch(void* const* d_in, const int* in_sizes, int n_in,
                              void* d_out, int out_size, void* d_ws, size_t ws_size,
                              hipStream_t stream) {
    const float* A = (const float*)d_in[0];
    const float* B = (const float*)d_in[1];
    float* out     = (float*)d_out;

    // ws: [partial 4s x 16bd x 4096 f32 = 1MB][ctrl: 17 u32 + 1 f32]
    float*    partial = (float*)d_ws;
    unsigned* ctrl    = (unsigned*)((char*)d_ws + (size_t)1024 * 1024);

    hipMemsetAsync(ctrl, 0, 256, stream);   // counters + sumacc = 0 (capturable)
    chamfer_fused_kernel<<<dim3(32, BATCH, 2), 256, 0, stream>>>(A, B, partial, ctrl, out);
}

// Round 10
// 79.349 us; speedup vs baseline: 1.3882x; 1.1473x over previous
//
#include <hip/hip_runtime.h>

// Chamfer-with-normals, B=8, C=6 (3 pos + 3 nrm), N=4096, fp32.
// d[i][j] = aa_i + (bb_j + W) + r_i.c_j,  r=(-2p_i, -W bn_i), c=(q_j, an_j)
// (cross-indexed normals; MFMA f16 hi/lo formulation verified absmax=0 R6-R9).
//
// R10: A/B verdict from R9 — the last-block tail costs ~17us in device-scope
// fences (per-XCD L2 writeback/invalidate) vs ~8us saved; revert to the R7
// two-dispatch structure (best total, 77us). Changes vs R7:
//  (1) DPP row_ror min epilogue (VALU pipe, verified R8/R9) replaces shfl_xor.
//  (2) col-split halved to 512 cols -> LDS 32KB -> 1024 blocks = 4 blocks/CU
//      = 4 waves/SIMD at launch_bounds(256,4) (~100 VGPR < 128, no spill;
//      R8 showed the register cliff at rt=16, R4 showed occupancy gains).
//   A32 = [rh6|rl6|rh6|rl6| 1 1 ah al |0000], B32 = [ch6|ch6|cl6|cl6| bh bl 1 1 |0000]
// Layouts m89/m120-verified; D[row=quad*4+reg][col=lane&15].

constexpr int   NPTS  = 4096;
constexpr int   CPB   = 6;
constexpr int   BATCH = 8;
constexpr float W     = 0.001f;

typedef _Float16 f16x8 __attribute__((ext_vector_type(8)));
typedef float    f32x4 __attribute__((ext_vector_type(4)));

#define MFMA32(A_, B_, C_) __builtin_amdgcn_mfma_f32_16x16x32_f16((A_), (B_), (C_), 0, 0, 0)

__device__ inline void fsplit(float x, _Float16& h, _Float16& l) {
    h = (_Float16)x;
    l = (_Float16)(x - (float)h);
}

// min with row_ror:N DPP (16-lane row rotation; all lanes valid) — VALU pipe.
template<int CTRL>
__device__ inline float minror(float v) {
    int s = __float_as_int(v);
    int r = __builtin_amdgcn_update_dpp(s, s, CTRL, 0xF, 0xF, false);
    return fminf(v, __int_as_float(r));
}

// Grid: x = rg*8 + s (rg: 8 groups of 512 rows; s: 8 splits of 512 cols),
// y = batch, z = dir => 1024 blocks = 4/CU. 256 thr; wave owns 128 rows (rt=8).
__global__ __launch_bounds__(256, 4) void chamfer_fused_kernel(
    const float* __restrict__ A, const float* __restrict__ B,
    float* __restrict__ partial, float* __restrict__ out)
{
    const int dir = blockIdx.z, batch = blockIdx.y, bd = dir * BATCH + batch;
    const int rg = blockIdx.x >> 3, s = blockIdx.x & 7;
    const int tid = threadIdx.x, w = tid >> 6, lane = tid & 63;
    const int quad = lane >> 4, l16 = lane & 15;
    const float* rowPos = dir ? B : A;
    const float* rowNrm = dir ? A : B;
    const float* colPos = dir ? A : B;
    const float* colNrm = dir ? B : A;
    const int bb = batch * CPB * NPTS;
    const _Float16 one = (_Float16)1.f, zz = (_Float16)0.f;

    if (blockIdx.x == 0 && blockIdx.y == 0 && blockIdx.z == 0 && tid == 0)
        out[0] = 0.f;                       // ordered before reduce's atomics

    // [k-plane][col][8 f16]: plane p at p*4096 f16 (8KB). Staging writes and
    // b-frag reads are both lane-consecutive 16B bursts (conflict-free b128).
    __shared__ alignas(16) _Float16 lds[4 * 512 * 8];    // 32 KB (4 blocks/CU)

    // ---- stage this block's 512 cols (2 cols per thread)
#pragma unroll
    for (int p = 0; p < 2; ++p) {
        const int j  = p * 256 + tid;
        const int cj = s * 512 + j;
        const float q0 = colPos[bb + 0*NPTS + cj], q1 = colPos[bb + 1*NPTS + cj],
                    q2 = colPos[bb + 2*NPTS + cj];
        const float n0 = colNrm[bb + 3*NPTS + cj], n1 = colNrm[bb + 4*NPTS + cj],
                    n2 = colNrm[bb + 5*NPTS + cj];
        const float c6[6] = {q0, q1, q2, n0, n1, n2};
        const float bias = fmaf(q0, q0, fmaf(q1, q1, q2*q2)) + W;
        _Float16 ch[6], cl[6], bh, bl;
#pragma unroll
        for (int c = 0; c < 6; ++c) fsplit(c6[c], ch[c], cl[c]);
        fsplit(bias, bh, bl);
        f16x8 v0 = {ch[0], ch[1], ch[2], ch[3], ch[4], ch[5], ch[0], ch[1]};
        f16x8 v1 = {ch[2], ch[3], ch[4], ch[5], cl[0], cl[1], cl[2], cl[3]};
        f16x8 v2 = {cl[4], cl[5], cl[0], cl[1], cl[2], cl[3], cl[4], cl[5]};
        f16x8 v3 = {bh, bl, one, one, zz, zz, zz, zz};
        *(f16x8*)&lds[0 * 4096 + j * 8] = v0;
        *(f16x8*)&lds[1 * 4096 + j * 8] = v1;
        *(f16x8*)&lds[2 * 4096 + j * 8] = v2;
        *(f16x8*)&lds[3 * 4096 + j * 8] = v3;
    }

    // ---- A-frags: rt=8 row-tiles per wave (wave owns 128 rows)
    f16x8 a[8];
#pragma unroll
    for (int rt = 0; rt < 8; ++rt) {
        const int row = rg * 512 + (w * 8 + rt) * 16 + l16;
        const float p0 = rowPos[bb + 0*NPTS + row], p1 = rowPos[bb + 1*NPTS + row],
                    p2 = rowPos[bb + 2*NPTS + row];
        const float rn0 = rowNrm[bb + 3*NPTS + row], rn1 = rowNrm[bb + 4*NPTS + row],
                    rn2 = rowNrm[bb + 5*NPTS + row];
        const float r6[6] = {-2.f*p0, -2.f*p1, -2.f*p2, -W*rn0, -W*rn1, -W*rn2};
        const float aa = fmaf(p0, p0, fmaf(p1, p1, p2*p2));
        _Float16 rh[6], rl[6], ah, al;
#pragma unroll
        for (int c = 0; c < 6; ++c) fsplit(r6[c], rh[c], rl[c]);
        fsplit(aa, ah, al);
        f16x8 af;
        if (quad == 0)      af = f16x8{rh[0], rh[1], rh[2], rh[3], rh[4], rh[5], rl[0], rl[1]};
        else if (quad == 1) af = f16x8{rl[2], rl[3], rl[4], rl[5], rh[0], rh[1], rh[2], rh[3]};
        else if (quad == 2) af = f16x8{rh[4], rh[5], rl[0], rl[1], rl[2], rl[3], rl[4], rl[5]};
        else                af = f16x8{one, one, ah, al, zz, zz, zz, zz};
        a[rt] = af;
    }

    float m[8][4];
#pragma unroll
    for (int rt = 0; rt < 8; ++rt)
#pragma unroll
        for (int r_ = 0; r_ < 4; ++r_) m[rt][r_] = 3.4e38f;

    __syncthreads();                        // the kernel's only barrier

    const _Float16* lq = &lds[quad * 4096];
    const f32x4 z = {0.f, 0.f, 0.f, 0.f};
    for (int ct = 0; ct < 32; ct += 2) {
        const f16x8 b0 = *(const f16x8*)&lq[(ct * 16 + l16) * 8];
        const f16x8 b1 = *(const f16x8*)&lq[((ct + 1) * 16 + l16) * 8];
#pragma unroll
        for (int rt = 0; rt < 8; ++rt) {
            f32x4 acc0 = MFMA32(a[rt], b0, z);
            f32x4 acc1 = MFMA32(a[rt], b1, z);
#pragma unroll
            for (int r_ = 0; r_ < 4; ++r_)
                m[rt][r_] = fminf(m[rt][r_], fminf(acc0[r_], acc1[r_]));  // v_min3
        }
    }

    // ---- col-min over l16 via DPP row_ror (VALU pipe, no DS traffic)
#pragma unroll
    for (int rt = 0; rt < 8; ++rt)
#pragma unroll
        for (int r_ = 0; r_ < 4; ++r_) {
            float v = m[rt][r_];
            v = minror<0x121>(v);   // ror 1
            v = minror<0x122>(v);   // ror 2
            v = minror<0x124>(v);   // ror 4
            v = minror<0x128>(v);   // ror 8
            m[rt][r_] = v;
        }
    if (l16 == 0) {
        float* pb = partial + (size_t)(s * 16 + bd) * NPTS + rg * 512;
#pragma unroll
        for (int rt = 0; rt < 8; ++rt)
            *(float4*)(pb + (w * 8 + rt) * 16 + quad * 4) =
                make_float4(m[rt][0], m[rt][1], m[rt][2], m[rt][3]);
    }
}

__global__ __launch_bounds__(256) void reduce_kernel(
    const float* __restrict__ partial, float* __restrict__ out)
{
    const int g = blockIdx.x * 256 + threadIdx.x;   // 0 .. 65535
    const int bd = g >> 12, row = g & (NPTS - 1);
    float v = partial[(size_t)(0 * 16 + bd) * NPTS + row];
#pragma unroll
    for (int s = 1; s < 8; ++s)
        v = fminf(v, partial[(size_t)(s * 16 + bd) * NPTS + row]);
    for (int off = 32; off; off >>= 1)
        v += __shfl_down(v, off, 64);
    __shared__ float sred[4];
    if ((threadIdx.x & 63) == 0) sred[threadIdx.x >> 6] = v;
    __syncthreads();
    if (threadIdx.x == 0)
        atomicAdd(out, (sred[0] + sred[1] + sred[2] + sred[3]) * 0.125f);  // /B
}

extern "C" void kernel_launch(void* const* d_in, const int* in_sizes, int n_in,
                              void* d_out, int out_size, void* d_ws, size_t ws_size,
                              hipStream_t stream) {
    const float* A = (const float*)d_in[0];
    const float* B = (const float*)d_in[1];
    float* out     = (float*)d_out;
    float* partial = (float*)d_ws;          // 8 splits x 16 bd x 4096 f32 = 2 MB

    chamfer_fused_kernel<<<dim3(64, BATCH, 2), 256, 0, stream>>>(A, B, partial, out);
    reduce_kernel<<<dim3(2 * BATCH * NPTS / 256), 256, 0, stream>>>(partial, out);
}